// Round 2
// baseline (9559.800 us; speedup 1.0000x reference)
//
#include <hip/hip_runtime.h>
#include <cstdint>
#include <cstddef>

#define BATCH 64
#define SEQ   128
#define EMB   512
#define HID   1024
#define NCLS  10000
#define NG    4096      // 4*HID gate columns
#define NOP   10048     // padded output columns (314 * 32)
#define NBLK  256       // persistent grid

typedef __attribute__((ext_vector_type(8))) short short8;
typedef __attribute__((ext_vector_type(4))) short short4v;
typedef __attribute__((ext_vector_type(4))) float floatx4;
typedef unsigned short u16;

__device__ __forceinline__ u16 f2bf(float x) {
    union { float f; unsigned u; } v; v.f = x;
    unsigned r = v.u + 0x7fffu + ((v.u >> 16) & 1u);   // RNE
    return (u16)(r >> 16);
}
__device__ __forceinline__ float sigm(float x) { return 1.f / (1.f + __expf(-x)); }

// ---------------------------------------------------------------------------
// Pack 4 gate matrices [K][1024] fp32 -> Wcat k-inner-8 bf16 layout:
//   element (k, col n) at dst[((k>>3)*NG + n)*8 + (k&7)],  n = unit*4 + gate.
// ---------------------------------------------------------------------------
__global__ void pack_gates(const float* __restrict__ s0, const float* __restrict__ s1,
                           const float* __restrict__ s2, const float* __restrict__ s3,
                           u16* __restrict__ dst, int kgroups, int kg_off) {
    int t = blockIdx.x * blockDim.x + threadIdx.x;
    if (t >= kgroups * HID) return;
    int u  = t & (HID - 1);
    int kg = t >> 10;
    u16* out = dst + ((size_t)(kg + kg_off) * NG + (size_t)u * 4) * 8;
#pragma unroll
    for (int g = 0; g < 4; ++g) {
        const float* s = (g == 0) ? s0 : (g == 1) ? s1 : (g == 2) ? s2 : s3;
        short8 v;
#pragma unroll
        for (int j = 0; j < 8; ++j)
            v[j] = (short)f2bf(s[(size_t)(kg * 8 + j) * HID + u]);
        *(short8*)(out + g * 8) = v;
    }
}

// W_out [1024][10000] fp32 -> padded k-inner-8 bf16 [(128)][10048][8]
__global__ void pack_wout(const float* __restrict__ src, u16* __restrict__ dst) {
    int t = blockIdx.x * blockDim.x + threadIdx.x;
    if (t >= 128 * NCLS) return;
    int n  = t % NCLS;
    int kg = t / NCLS;
    short8 v;
#pragma unroll
    for (int j = 0; j < 8; ++j)
        v[j] = (short)f2bf(src[(size_t)(kg * 8 + j) * NCLS + n]);
    *(short8*)(dst + ((size_t)kg * NOP + n) * 8) = v;
}

// E[s][b][:] = bf16(C[X[b][s]][:])   (E laid out [SEQ][BATCH][EMB])
__global__ void embed_k(const int* __restrict__ X, const float* __restrict__ C,
                        u16* __restrict__ E) {
    const int sb = blockIdx.x;             // s*64 + m
    const int s = sb >> 6, m = sb & 63;
    const int row = X[m * SEQ + s];
    const floatx4* src = (const floatx4*)(C + (size_t)row * EMB);
    u16* dst = E + (size_t)sb * EMB;
    const int t = threadIdx.x;             // 128 threads, 4 elems each
    floatx4 v = src[t];
    short4v o;
    o[0] = (short)f2bf(v[0]); o[1] = (short)f2bf(v[1]);
    o[2] = (short)f2bf(v[2]); o[3] = (short)f2bf(v[3]);
    *(short4v*)(dst + t * 4) = o;
}

// ---------------------------------------------------------------------------
// Device-scope grid barrier (monotonic counter, sense-free).
// All NBLK blocks call it the same number of times; target = phase*NBLK.
// __threadfence() = agent-scope release (flushes per-XCD L2 writebacks);
// acquire-load invalidates L1/L2 so post-barrier reads see remote writes.
// ---------------------------------------------------------------------------
__device__ __forceinline__ void grid_sync(unsigned* cnt, unsigned target) {
    __threadfence();
    __syncthreads();
    if (threadIdx.x == 0) {
        __hip_atomic_fetch_add(cnt, 1u, __ATOMIC_RELEASE, __HIP_MEMORY_SCOPE_AGENT);
        while (__hip_atomic_load(cnt, __ATOMIC_ACQUIRE, __HIP_MEMORY_SCOPE_AGENT) < target)
            __builtin_amdgcn_s_sleep(1);
    }
    __syncthreads();
}

// ---------------------------------------------------------------------------
// One LSTM step for this block's 32 gate cols (8 units). Same MFMA structure
// as round 1 (verified): 4 waves k-split, LDS reduce, fused gate math.
// ---------------------------------------------------------------------------
template<int K1, int NCH>
__device__ __forceinline__ void step_dev(
    float (*red)[64][33], int ub,
    const u16* __restrict__ Xt, const u16* __restrict__ hin,
    u16* __restrict__ hout, u16* __restrict__ Hout,
    float* __restrict__ cst, const u16* __restrict__ W,
    const float* __restrict__ bfp, const float* __restrict__ bip,
    const float* __restrict__ bCp, const float* __restrict__ bop)
{
    const int tid = threadIdx.x;
    const int w = tid >> 6, l = tid & 63;
    const int ml = l & 15, q = l >> 4;
    const int n0 = ub * 32;

    floatx4 acc[4][2];
#pragma unroll
    for (int mi = 0; mi < 4; ++mi)
#pragma unroll
        for (int ni = 0; ni < 2; ++ni)
            acc[mi][ni] = (floatx4){0.f, 0.f, 0.f, 0.f};

#pragma unroll 4
    for (int ci = 0; ci < NCH / 4; ++ci) {
        const int k = (ci * 4 + w) << 5;              // wave-uniform
        const u16* Ab; int lda, kl;
        if (k < K1) { Ab = Xt;  lda = K1;  kl = k; }
        else        { Ab = hin; lda = HID; kl = k - K1; }
        const u16* ar = Ab + (size_t)ml * lda + kl + q * 8;
        short8 a0 = *(const short8*)(ar);
        short8 a1 = *(const short8*)(ar + (size_t)16 * lda);
        short8 a2 = *(const short8*)(ar + (size_t)32 * lda);
        short8 a3 = *(const short8*)(ar + (size_t)48 * lda);
        const u16* br = W + ((size_t)((k >> 3) + q) * NG + n0 + ml) * 8;
        short8 b0 = *(const short8*)(br);
        short8 b1 = *(const short8*)(br + 16 * 8);
        acc[0][0] = __builtin_amdgcn_mfma_f32_16x16x32_bf16(a0, b0, acc[0][0], 0, 0, 0);
        acc[1][0] = __builtin_amdgcn_mfma_f32_16x16x32_bf16(a1, b0, acc[1][0], 0, 0, 0);
        acc[2][0] = __builtin_amdgcn_mfma_f32_16x16x32_bf16(a2, b0, acc[2][0], 0, 0, 0);
        acc[3][0] = __builtin_amdgcn_mfma_f32_16x16x32_bf16(a3, b0, acc[3][0], 0, 0, 0);
        acc[0][1] = __builtin_amdgcn_mfma_f32_16x16x32_bf16(a0, b1, acc[0][1], 0, 0, 0);
        acc[1][1] = __builtin_amdgcn_mfma_f32_16x16x32_bf16(a1, b1, acc[1][1], 0, 0, 0);
        acc[2][1] = __builtin_amdgcn_mfma_f32_16x16x32_bf16(a2, b1, acc[2][1], 0, 0, 0);
        acc[3][1] = __builtin_amdgcn_mfma_f32_16x16x32_bf16(a3, b1, acc[3][1], 0, 0, 0);
    }

#pragma unroll
    for (int mi = 0; mi < 4; ++mi)
#pragma unroll
        for (int ni = 0; ni < 2; ++ni)
#pragma unroll
            for (int r = 0; r < 4; ++r)
                red[w][mi * 16 + q * 4 + r][ni * 16 + ml] = acc[mi][ni][r];
    __syncthreads();

    const int m = tid >> 2;
#pragma unroll
    for (int hh = 0; hh < 2; ++hh) {
        const int u  = (tid & 3) + hh * 4;            // local unit 0..7
        const int ug = ub * 8 + u;                    // global unit
        const int nl = u * 4;
        float p0 = red[0][m][nl+0] + red[1][m][nl+0] + red[2][m][nl+0] + red[3][m][nl+0];
        float p1 = red[0][m][nl+1] + red[1][m][nl+1] + red[2][m][nl+1] + red[3][m][nl+1];
        float p2 = red[0][m][nl+2] + red[1][m][nl+2] + red[2][m][nl+2] + red[3][m][nl+2];
        float p3 = red[0][m][nl+3] + red[1][m][nl+3] + red[2][m][nl+3] + red[3][m][nl+3];
        float f = sigm(p0 + bfp[ug]);
        float i = sigm(p1 + bip[ug]);
        float g = tanhf(p2 + bCp[ug]);
        float o = sigm(p3 + bop[ug]);
        float c = f * cst[m * HID + ug] + i * g;
        cst[m * HID + ug] = c;
        u16 hb = f2bf(o * tanhf(c));
        hout[m * HID + ug] = hb;
        if (Hout) Hout[m * HID + ug] = hb;
    }
}

// out tile: 32 cols of out[64][10000] = h1 @ W_out + b_out
__device__ __forceinline__ void out_dev(
    float (*red)[64][33], int tile,
    const u16* __restrict__ h1, const u16* __restrict__ W,
    const float* __restrict__ bout, float* __restrict__ out)
{
    __syncthreads();                                  // red reuse guard
    const int tid = threadIdx.x;
    const int w = tid >> 6, l = tid & 63;
    const int ml = l & 15, q = l >> 4;
    const int n0 = tile * 32;

    floatx4 acc[4][2];
#pragma unroll
    for (int mi = 0; mi < 4; ++mi)
#pragma unroll
        for (int ni = 0; ni < 2; ++ni)
            acc[mi][ni] = (floatx4){0.f, 0.f, 0.f, 0.f};

#pragma unroll
    for (int ci = 0; ci < 8; ++ci) {
        const int k = (ci * 4 + w) << 5;
        const u16* ar = h1 + (size_t)ml * HID + k + q * 8;
        short8 a0 = *(const short8*)(ar);
        short8 a1 = *(const short8*)(ar + 16 * HID);
        short8 a2 = *(const short8*)(ar + 32 * HID);
        short8 a3 = *(const short8*)(ar + 48 * HID);
        const u16* br = W + ((size_t)((k >> 3) + q) * NOP + n0 + ml) * 8;
        short8 b0 = *(const short8*)(br);
        short8 b1 = *(const short8*)(br + 16 * 8);
        acc[0][0] = __builtin_amdgcn_mfma_f32_16x16x32_bf16(a0, b0, acc[0][0], 0, 0, 0);
        acc[1][0] = __builtin_amdgcn_mfma_f32_16x16x32_bf16(a1, b0, acc[1][0], 0, 0, 0);
        acc[2][0] = __builtin_amdgcn_mfma_f32_16x16x32_bf16(a2, b0, acc[2][0], 0, 0, 0);
        acc[3][0] = __builtin_amdgcn_mfma_f32_16x16x32_bf16(a3, b0, acc[3][0], 0, 0, 0);
        acc[0][1] = __builtin_amdgcn_mfma_f32_16x16x32_bf16(a0, b1, acc[0][1], 0, 0, 0);
        acc[1][1] = __builtin_amdgcn_mfma_f32_16x16x32_bf16(a1, b1, acc[1][1], 0, 0, 0);
        acc[2][1] = __builtin_amdgcn_mfma_f32_16x16x32_bf16(a2, b1, acc[2][1], 0, 0, 0);
        acc[3][1] = __builtin_amdgcn_mfma_f32_16x16x32_bf16(a3, b1, acc[3][1], 0, 0, 0);
    }

#pragma unroll
    for (int mi = 0; mi < 4; ++mi)
#pragma unroll
        for (int ni = 0; ni < 2; ++ni)
#pragma unroll
            for (int r = 0; r < 4; ++r)
                red[w][mi * 16 + q * 4 + r][ni * 16 + ml] = acc[mi][ni][r];
    __syncthreads();

    const int m = tid >> 2;
#pragma unroll
    for (int jj = 0; jj < 8; ++jj) {
        const int nl = (tid & 3) * 8 + jj;
        const int n = n0 + nl;
        if (n < NCLS) {
            float v = red[0][m][nl] + red[1][m][nl] + red[2][m][nl] + red[3][m][nl] + bout[n];
            out[(size_t)m * NCLS + n] = v;
        }
    }
}

// ---------------------------------------------------------------------------
// Persistent kernel: 129 ticks, 2-layer pipeline, then output GEMM.
//   blocks   0..127: layer 0, step t      (t = 0..127)
//   blocks 128..255: layer 1, step t-1    (t = 1..128)
// 256 blocks x 256 thr, 34 KB LDS -> capacity ~4 blocks/CU, grid == #CUs:
// all blocks co-resident under a normal launch (no cooperative needed).
// ---------------------------------------------------------------------------
struct PArgs {
    const u16 *E, *Wcat0, *Wcat1, *WoutP;
    u16 *H, *h0a, *h0b, *h1a, *h1b;
    float *c0, *c1;
    const float *b_f, *b_i, *b_C, *b_o, *b_f1, *b_i1, *b_C1, *b_o1, *b_out;
    float* out;
    unsigned* barcnt;
};

__global__ void __launch_bounds__(256) persist_k(PArgs a) {
    __shared__ float red[4][64][33];
    const int b = blockIdx.x;
    unsigned tgt = 0;

    if (b < 128) {
        const int ub = b;
        for (int t = 0; t < 129; ++t) {
            if (t < 128) {
                const u16* hin = (t & 1) ? a.h0b : a.h0a;
                u16*       ho  = (t & 1) ? a.h0a : a.h0b;
                step_dev<512, 48>(red, ub, a.E + (size_t)t * BATCH * EMB, hin, ho,
                                  a.H + (size_t)t * BATCH * HID, a.c0, a.Wcat0,
                                  a.b_f, a.b_i, a.b_C, a.b_o);
            }
            tgt += NBLK; grid_sync(a.barcnt, tgt);
        }
    } else {
        const int ub = b - 128;
        for (int t = 0; t < 129; ++t) {
            if (t >= 1) {
                const int s = t - 1;
                const u16* hin = (s & 1) ? a.h1b : a.h1a;
                u16*       ho  = (s & 1) ? a.h1a : a.h1b;
                step_dev<1024, 64>(red, ub, a.H + (size_t)s * BATCH * HID, hin, ho,
                                   nullptr, a.c1, a.Wcat1,
                                   a.b_f1, a.b_i1, a.b_C1, a.b_o1);
            }
            tgt += NBLK; grid_sync(a.barcnt, tgt);
        }
    }

    // output GEMM: final h1 is in h1a (step 127 writes parity 0)
    for (int tile = b; tile < 314; tile += NBLK)
        out_dev(red, tile, a.h1a, a.WoutP, a.b_out, a.out);
}

// ---------------------------------------------------------------------------
extern "C" void kernel_launch(void* const* d_in, const int* in_sizes, int n_in,
                              void* d_out, int out_size, void* d_ws, size_t ws_size,
                              hipStream_t stream) {
    (void)in_sizes; (void)n_in; (void)out_size; (void)ws_size;
    const int*   X     = (const int*)  d_in[0];
    const float* C     = (const float*)d_in[1];
    const float* W_fx  = (const float*)d_in[2];
    const float* W_fh  = (const float*)d_in[3];
    const float* W_ix  = (const float*)d_in[4];
    const float* W_ih  = (const float*)d_in[5];
    const float* W_Cx  = (const float*)d_in[6];
    const float* W_Ch  = (const float*)d_in[7];
    const float* W_ox  = (const float*)d_in[8];
    const float* W_oh  = (const float*)d_in[9];
    const float* W_fx1 = (const float*)d_in[10];
    const float* W_fh1 = (const float*)d_in[11];
    const float* W_ix1 = (const float*)d_in[12];
    // d_in[13] = W_ih1 — unused: reference reuses W_ih in layer-1 i-gate (bug kept)
    const float* W_Cx1 = (const float*)d_in[14];
    const float* W_Ch1 = (const float*)d_in[15];
    const float* W_ox1 = (const float*)d_in[16];
    const float* W_oh1 = (const float*)d_in[17];
    const float* W_out = (const float*)d_in[18];
    const float* b_f   = (const float*)d_in[19];
    const float* b_i   = (const float*)d_in[20];
    const float* b_C   = (const float*)d_in[21];
    const float* b_o   = (const float*)d_in[22];
    const float* b_f1  = (const float*)d_in[23];
    const float* b_i1  = (const float*)d_in[24];
    const float* b_C1  = (const float*)d_in[25];
    const float* b_o1  = (const float*)d_in[26];
    const float* b_out = (const float*)d_in[27];
    float* out = (float*)d_out;

    // workspace carve
    uint8_t* ws = (uint8_t*)d_ws;
    const size_t SZ_WCAT0 = (size_t)1536 * NG * 2;    // 12 MB
    const size_t SZ_WCAT1 = (size_t)2048 * NG * 2;    // 16 MB
    const size_t SZ_WOUTP = (size_t)1024 * NOP * 2;   // ~20 MB
    const size_t SZ_E     = (size_t)SEQ * BATCH * EMB * 2;   // 8 MB
    const size_t SZ_H     = (size_t)SEQ * BATCH * HID * 2;   // 16 MB
    const size_t SZ_HB    = (size_t)BATCH * HID * 2;         // 128 KB
    const size_t SZ_C     = (size_t)BATCH * HID * 4;         // 256 KB
    u16*   Wcat0 = (u16*)ws;                         ws += SZ_WCAT0;
    u16*   Wcat1 = (u16*)ws;                         ws += SZ_WCAT1;
    u16*   WoutP = (u16*)ws;                         ws += SZ_WOUTP;
    u16*   E     = (u16*)ws;                         ws += SZ_E;
    u16*   H     = (u16*)ws;                         ws += SZ_H;
    u16*   h0a   = (u16*)ws;                         ws += SZ_HB;
    u16*   h0b   = (u16*)ws;                         ws += SZ_HB;
    u16*   h1a   = (u16*)ws;                         ws += SZ_HB;
    u16*   h1b   = (u16*)ws;                         ws += SZ_HB;
    float* c0    = (float*)ws;                       ws += SZ_C;
    float* c1    = (float*)ws;                       ws += SZ_C;
    unsigned* barcnt = (unsigned*)ws;                ws += 256;

    // --- pack weights + embed (parallel prep work)
    pack_gates<<<256, 256, 0, stream>>>(W_fx, W_ix, W_Cx, W_ox, Wcat0, 64, 0);
    pack_gates<<<512, 256, 0, stream>>>(W_fh, W_ih, W_Ch, W_oh, Wcat0, 128, 64);
    pack_gates<<<512, 256, 0, stream>>>(W_fx1, W_ix1, W_Cx1, W_ox1, Wcat1, 128, 0);
    pack_gates<<<512, 256, 0, stream>>>(W_fh1, W_ih, W_Ch1, W_oh1, Wcat1, 128, 128);
    hipMemsetAsync(WoutP, 0, SZ_WOUTP, stream);
    pack_wout<<<(128 * NCLS + 255) / 256, 256, 0, stream>>>(W_out, WoutP);
    embed_k<<<SEQ * BATCH, 128, 0, stream>>>(X, C, E);

    // --- zero state + barrier counter (ws is re-poisoned before every call)
    hipMemsetAsync(h0a, 0, SZ_HB, stream);
    hipMemsetAsync(h1a, 0, SZ_HB, stream);
    hipMemsetAsync(c0, 0, SZ_C, stream);
    hipMemsetAsync(c1, 0, SZ_C, stream);
    hipMemsetAsync(barcnt, 0, 256, stream);

    // --- the whole recurrence + output projection in one launch
    PArgs pa;
    pa.E = E; pa.Wcat0 = Wcat0; pa.Wcat1 = Wcat1; pa.WoutP = WoutP;
    pa.H = H; pa.h0a = h0a; pa.h0b = h0b; pa.h1a = h1a; pa.h1b = h1b;
    pa.c0 = c0; pa.c1 = c1;
    pa.b_f = b_f; pa.b_i = b_i; pa.b_C = b_C; pa.b_o = b_o;
    pa.b_f1 = b_f1; pa.b_i1 = b_i1; pa.b_C1 = b_C1; pa.b_o1 = b_o1;
    pa.b_out = b_out; pa.out = out; pa.barcnt = barcnt;
    persist_k<<<NBLK, 256, 0, stream>>>(pa);
}

// Round 3
// 6337.565 us; speedup vs baseline: 1.5084x; 1.5084x over previous
//
#include <hip/hip_runtime.h>
#include <cstdint>
#include <cstddef>

#define BATCH 64
#define SEQ   128
#define EMB   512
#define HID   1024
#define NCLS  10000
#define NG    4096      // 4*HID gate columns
#define NOP   10048     // padded output columns (314 * 32)

typedef __attribute__((ext_vector_type(8))) short short8;
typedef __attribute__((ext_vector_type(4))) short short4v;
typedef __attribute__((ext_vector_type(4))) float floatx4;
typedef unsigned short u16;

// dynamic LDS: 128 KB W slice + red[2][64][33] fp32
#define LDS_W_U16  65536
#define LDS_BYTES  (131072 + 2*64*33*4)   // 147968

__device__ __forceinline__ u16 f2bf(float x) {
    union { float f; unsigned u; } v; v.f = x;
    unsigned r = v.u + 0x7fffu + ((v.u >> 16) & 1u);   // RNE
    return (u16)(r >> 16);
}
__device__ __forceinline__ float sigm(float x) { return 1.f / (1.f + __expf(-x)); }

// ---------------------------------------------------------------------------
// Pack 4 gate matrices [K][1024] fp32 -> Wcat k-inner-8 bf16 layout:
//   element (k, col n) at dst[((k>>3)*NG + n)*8 + (k&7)],  n = unit*4 + gate.
// ---------------------------------------------------------------------------
__global__ void pack_gates(const float* __restrict__ s0, const float* __restrict__ s1,
                           const float* __restrict__ s2, const float* __restrict__ s3,
                           u16* __restrict__ dst, int kgroups, int kg_off) {
    int t = blockIdx.x * blockDim.x + threadIdx.x;
    if (t >= kgroups * HID) return;
    int u  = t & (HID - 1);
    int kg = t >> 10;
    u16* out = dst + ((size_t)(kg + kg_off) * NG + (size_t)u * 4) * 8;
#pragma unroll
    for (int g = 0; g < 4; ++g) {
        const float* s = (g == 0) ? s0 : (g == 1) ? s1 : (g == 2) ? s2 : s3;
        short8 v;
#pragma unroll
        for (int j = 0; j < 8; ++j)
            v[j] = (short)f2bf(s[(size_t)(kg * 8 + j) * HID + u]);
        *(short8*)(out + g * 8) = v;
    }
}

// W_out [1024][10000] fp32 -> padded k-inner-8 bf16 [(128)][10048][8]
__global__ void pack_wout(const float* __restrict__ src, u16* __restrict__ dst) {
    int t = blockIdx.x * blockDim.x + threadIdx.x;
    if (t >= 128 * NCLS) return;
    int n  = t % NCLS;
    int kg = t / NCLS;
    short8 v;
#pragma unroll
    for (int j = 0; j < 8; ++j)
        v[j] = (short)f2bf(src[(size_t)(kg * 8 + j) * NCLS + n]);
    *(short8*)(dst + ((size_t)kg * NOP + n) * 8) = v;
}

// E[s][b][:] = bf16(C[X[b][s]][:])   (E laid out [SEQ][BATCH][EMB])
__global__ void embed_k(const int* __restrict__ X, const float* __restrict__ C,
                        u16* __restrict__ E) {
    const int sb = blockIdx.x;             // s*64 + m
    const int s = sb >> 6, m = sb & 63;
    const int row = X[m * SEQ + s];
    const floatx4* src = (const floatx4*)(C + (size_t)row * EMB);
    u16* dst = E + (size_t)sb * EMB;
    const int t = threadIdx.x;             // 128 threads, 4 elems each
    floatx4 v = src[t];
    short4v o;
    o[0] = (short)f2bf(v[0]); o[1] = (short)f2bf(v[1]);
    o[2] = (short)f2bf(v[2]); o[3] = (short)f2bf(v[3]);
    *(short4v*)(dst + t * 4) = o;
}

// ---------------------------------------------------------------------------
// One LSTM step. Wave partition: 2-way K-split x 2-way M-split (w = km + 2*mw).
// Wave (km,mw): rows mw*32..+31, all 32 cols, k-half km. B from LDS (WL),
// A from global. fp32 partials reduced across the 2 k-halves via LDS red.
// MFMA 16x16x32 frag layouts (verified m89/m91).
// c-state and biases live in registers (thread mapping is tick-invariant).
// ---------------------------------------------------------------------------
template<int K1, int CHH>
__device__ __forceinline__ void step_dev(
    u16* __restrict__ WL, float (*red)[64][33],
    const u16* __restrict__ Xt, const u16* __restrict__ hin,
    u16* __restrict__ ho, u16* __restrict__ Hout,
    float* c, const float* bF, const float* bI, const float* bCv, const float* bO,
    int ub)
{
    const int tid = threadIdx.x;
    const int w = tid >> 6, l = tid & 63;
    const int ml = l & 15, q = l >> 4;
    const int km = w & 1, mw = w >> 1;
    const int r0 = mw * 32;

    floatx4 acc[2][2];
#pragma unroll
    for (int mi = 0; mi < 2; ++mi)
#pragma unroll
        for (int ni = 0; ni < 2; ++ni)
            acc[mi][ni] = (floatx4){0.f, 0.f, 0.f, 0.f};

#pragma unroll 4
    for (int ci = 0; ci < CHH; ++ci) {
        const int k = (km * CHH + ci) * 32;           // wave-uniform global k
        const u16* Ab; int lda, kl;
        if (k < K1) { Ab = Xt;  lda = K1;  kl = k; }
        else        { Ab = hin; lda = HID; kl = k - K1; }
        const u16* ar = Ab + (size_t)(r0 + ml) * lda + kl + q * 8;
        short8 a0 = *(const short8*)(ar);
        short8 a1 = *(const short8*)(ar + (size_t)16 * lda);
        const u16* br = WL + ((size_t)(((k >> 3) + q) * 32 + ml)) * 8;
        short8 b0 = *(const short8*)(br);
        short8 b1 = *(const short8*)(br + 16 * 8);
        acc[0][0] = __builtin_amdgcn_mfma_f32_16x16x32_bf16(a0, b0, acc[0][0], 0, 0, 0);
        acc[1][0] = __builtin_amdgcn_mfma_f32_16x16x32_bf16(a1, b0, acc[1][0], 0, 0, 0);
        acc[0][1] = __builtin_amdgcn_mfma_f32_16x16x32_bf16(a0, b1, acc[0][1], 0, 0, 0);
        acc[1][1] = __builtin_amdgcn_mfma_f32_16x16x32_bf16(a1, b1, acc[1][1], 0, 0, 0);
    }

#pragma unroll
    for (int mi = 0; mi < 2; ++mi)
#pragma unroll
        for (int ni = 0; ni < 2; ++ni)
#pragma unroll
            for (int r = 0; r < 4; ++r)
                red[km][r0 + mi * 16 + q * 4 + r][ni * 16 + ml] = acc[mi][ni][r];
    __syncthreads();

    const int m = tid >> 2;
#pragma unroll
    for (int hh = 0; hh < 2; ++hh) {
        const int u  = (tid & 3) + hh * 4;            // local unit 0..7
        const int ug = ub * 8 + u;                    // global unit
        const int nl = u * 4;
        float p0 = red[0][m][nl+0] + red[1][m][nl+0];
        float p1 = red[0][m][nl+1] + red[1][m][nl+1];
        float p2 = red[0][m][nl+2] + red[1][m][nl+2];
        float p3 = red[0][m][nl+3] + red[1][m][nl+3];
        float f = sigm(p0 + bF[hh]);
        float i = sigm(p1 + bI[hh]);
        float g = tanhf(p2 + bCv[hh]);
        float o = sigm(p3 + bO[hh]);
        float cc = f * c[hh] + i * g;
        c[hh] = cc;
        u16 hb = f2bf(o * tanhf(cc));
        ho[m * HID + ug] = hb;
        if (Hout) Hout[m * HID + ug] = hb;
    }
    // red reuse protected by the sync sequence following each step
}

// ---------------------------------------------------------------------------
// Persistent kernel. Grid 256 x 256thr, 147968 B dynamic LDS -> 1 block/CU,
// grid == #CUs: all blocks co-resident under a normal launch.
//   blocks   0..127: layer 0, steps 0..127 (barrier bar0 among themselves,
//                    release hcnt after writing H[t])
//   blocks 128..255: layer 1, steps 0..127 (wait hcnt, barrier bar1)
// Sync discipline (the round-2 lesson): RELAXED arrive + RELAXED poll +
// single __threadfence() after poll exit (tid0 only; 1 block/CU so its cache
// invalidation covers the whole block). Never acquire inside the spin loop.
// ---------------------------------------------------------------------------
struct PArgs {
    const u16 *E, *Wcat0, *Wcat1;
    u16 *H, *h0a, *h0b, *h1a, *h1b;
    const float *b_f, *b_i, *b_C, *b_o, *b_f1, *b_i1, *b_C1, *b_o1;
    unsigned* sync;   // [0]=bar0, [64]=bar1, [128]=hcnt (separate cachelines)
};

__global__ void __launch_bounds__(256) persist_k(PArgs a) {
    extern __shared__ u16 lds[];
    u16* WL = lds;
    float (*red)[64][33] = (float (*)[64][33])(lds + LDS_W_U16);

    const int b   = blockIdx.x;
    const int ub  = b & 127;
    const int tid = threadIdx.x;
    const bool L0 = (b < 128);

    // stage this block's W slice into LDS (k-inner-8, 32 local cols)
    {
        const u16* Wsrc = L0 ? a.Wcat0 : a.Wcat1;
        const int  kgs  = L0 ? 192 : 256;
        for (int i = tid; i < kgs * 32; i += 256) {
            const int kg = i >> 5, cc = i & 31;
            *(short8*)(WL + ((size_t)(kg * 32 + cc)) * 8) =
                *(const short8*)(Wsrc + ((size_t)kg * NG + ub * 32 + cc) * 8);
        }
    }
    __syncthreads();

    // per-thread state: cell c and biases (mapping fixed across ticks)
    float c[2] = {0.f, 0.f};
    float bF[2], bI[2], bC[2], bO[2];
#pragma unroll
    for (int hh = 0; hh < 2; ++hh) {
        const int ug = ub * 8 + (tid & 3) + hh * 4;
        bF[hh] = L0 ? a.b_f[ug] : a.b_f1[ug];
        bI[hh] = L0 ? a.b_i[ug] : a.b_i1[ug];
        bC[hh] = L0 ? a.b_C[ug] : a.b_C1[ug];
        bO[hh] = L0 ? a.b_o[ug] : a.b_o1[ug];
    }

    unsigned* bar0 = a.sync;
    unsigned* bar1 = a.sync + 64;
    unsigned* hcnt = a.sync + 128;

    if (L0) {
        for (int t = 0; t < 128; ++t) {
            const u16* hin = (t & 1) ? a.h0b : a.h0a;
            u16*       ho  = (t & 1) ? a.h0a : a.h0b;
            step_dev<512, 24>(WL, red, a.E + (size_t)t * BATCH * EMB, hin, ho,
                              a.H + (size_t)t * BATCH * HID, c, bF, bI, bC, bO, ub);
            __threadfence();          // release our h/H writes (per-thread: vmcnt drain + L2 wb)
            __syncthreads();
            if (tid == 0) {
                __hip_atomic_fetch_add(hcnt, 1u, __ATOMIC_RELAXED, __HIP_MEMORY_SCOPE_AGENT);
                __hip_atomic_fetch_add(bar0, 1u, __ATOMIC_RELAXED, __HIP_MEMORY_SCOPE_AGENT);
                const unsigned tgt = 128u * (unsigned)(t + 1);
                while (__hip_atomic_load(bar0, __ATOMIC_RELAXED, __HIP_MEMORY_SCOPE_AGENT) < tgt)
                    __builtin_amdgcn_s_sleep(2);
                __threadfence();      // acquire: invalidate L1/L2 once, after the wait
            }
            __syncthreads();
        }
    } else {
        for (int s = 0; s < 128; ++s) {
            if (tid == 0) {
                const unsigned tgt = 128u * (unsigned)(s + 1);
                while (__hip_atomic_load(hcnt, __ATOMIC_RELAXED, __HIP_MEMORY_SCOPE_AGENT) < tgt)
                    __builtin_amdgcn_s_sleep(2);
                __threadfence();      // acquire before reading H[s]
            }
            __syncthreads();
            const u16* hin = (s & 1) ? a.h1b : a.h1a;
            u16*       ho  = (s & 1) ? a.h1a : a.h1b;
            step_dev<1024, 32>(WL, red, a.H + (size_t)s * BATCH * HID, hin, ho,
                               nullptr, c, bF, bI, bC, bO, ub);
            __threadfence();
            __syncthreads();
            if (tid == 0) {
                __hip_atomic_fetch_add(bar1, 1u, __ATOMIC_RELAXED, __HIP_MEMORY_SCOPE_AGENT);
                const unsigned tgt = 128u * (unsigned)(s + 1);
                while (__hip_atomic_load(bar1, __ATOMIC_RELAXED, __HIP_MEMORY_SCOPE_AGENT) < tgt)
                    __builtin_amdgcn_s_sleep(2);
                __threadfence();
            }
            __syncthreads();
        }
    }
    // final h1 in h1a (step 127 writes parity 0); out_gemm is a separate launch
}

// out[64][10000] = h1 @ W_out + b_out   (314 blocks x 32 cols) — round-1 verified
__global__ void __launch_bounds__(256) out_gemm(
    const u16* __restrict__ h1, const u16* __restrict__ W,
    const float* __restrict__ bout, float* __restrict__ out)
{
    __shared__ float red[4][64][33];
    const int tid = threadIdx.x;
    const int w = tid >> 6, l = tid & 63;
    const int ml = l & 15, q = l >> 4;
    const int n0 = blockIdx.x * 32;

    floatx4 acc[4][2];
#pragma unroll
    for (int mi = 0; mi < 4; ++mi)
#pragma unroll
        for (int ni = 0; ni < 2; ++ni)
            acc[mi][ni] = (floatx4){0.f, 0.f, 0.f, 0.f};

#pragma unroll
    for (int ci = 0; ci < 8; ++ci) {
        const int k = (ci * 4 + w) << 5;
        const u16* ar = h1 + (size_t)ml * HID + k + q * 8;
        short8 a0 = *(const short8*)(ar);
        short8 a1 = *(const short8*)(ar + 16 * HID);
        short8 a2 = *(const short8*)(ar + 32 * HID);
        short8 a3 = *(const short8*)(ar + 48 * HID);
        const u16* br = W + ((size_t)((k >> 3) + q) * NOP + n0 + ml) * 8;
        short8 b0 = *(const short8*)(br);
        short8 b1 = *(const short8*)(br + 16 * 8);
        acc[0][0] = __builtin_amdgcn_mfma_f32_16x16x32_bf16(a0, b0, acc[0][0], 0, 0, 0);
        acc[1][0] = __builtin_amdgcn_mfma_f32_16x16x32_bf16(a1, b0, acc[1][0], 0, 0, 0);
        acc[2][0] = __builtin_amdgcn_mfma_f32_16x16x32_bf16(a2, b0, acc[2][0], 0, 0, 0);
        acc[3][0] = __builtin_amdgcn_mfma_f32_16x16x32_bf16(a3, b0, acc[3][0], 0, 0, 0);
        acc[0][1] = __builtin_amdgcn_mfma_f32_16x16x32_bf16(a0, b1, acc[0][1], 0, 0, 0);
        acc[1][1] = __builtin_amdgcn_mfma_f32_16x16x32_bf16(a1, b1, acc[1][1], 0, 0, 0);
        acc[2][1] = __builtin_amdgcn_mfma_f32_16x16x32_bf16(a2, b1, acc[2][1], 0, 0, 0);
        acc[3][1] = __builtin_amdgcn_mfma_f32_16x16x32_bf16(a3, b1, acc[3][1], 0, 0, 0);
    }

#pragma unroll
    for (int mi = 0; mi < 4; ++mi)
#pragma unroll
        for (int ni = 0; ni < 2; ++ni)
#pragma unroll
            for (int r = 0; r < 4; ++r)
                red[w][mi * 16 + q * 4 + r][ni * 16 + ml] = acc[mi][ni][r];
    __syncthreads();

    const int m = tid >> 2;
#pragma unroll
    for (int jj = 0; jj < 8; ++jj) {
        const int nl = (tid & 3) * 8 + jj;
        const int n = n0 + nl;
        if (n < NCLS) {
            float v = red[0][m][nl] + red[1][m][nl] + red[2][m][nl] + red[3][m][nl] + bout[n];
            out[(size_t)m * NCLS + n] = v;
        }
    }
}

// ---------------------------------------------------------------------------
extern "C" void kernel_launch(void* const* d_in, const int* in_sizes, int n_in,
                              void* d_out, int out_size, void* d_ws, size_t ws_size,
                              hipStream_t stream) {
    (void)in_sizes; (void)n_in; (void)out_size; (void)ws_size;
    const int*   X     = (const int*)  d_in[0];
    const float* C     = (const float*)d_in[1];
    const float* W_fx  = (const float*)d_in[2];
    const float* W_fh  = (const float*)d_in[3];
    const float* W_ix  = (const float*)d_in[4];
    const float* W_ih  = (const float*)d_in[5];
    const float* W_Cx  = (const float*)d_in[6];
    const float* W_Ch  = (const float*)d_in[7];
    const float* W_ox  = (const float*)d_in[8];
    const float* W_oh  = (const float*)d_in[9];
    const float* W_fx1 = (const float*)d_in[10];
    const float* W_fh1 = (const float*)d_in[11];
    const float* W_ix1 = (const float*)d_in[12];
    // d_in[13] = W_ih1 — unused: reference reuses W_ih in layer-1 i-gate (bug kept)
    const float* W_Cx1 = (const float*)d_in[14];
    const float* W_Ch1 = (const float*)d_in[15];
    const float* W_ox1 = (const float*)d_in[16];
    const float* W_oh1 = (const float*)d_in[17];
    const float* W_out = (const float*)d_in[18];
    const float* b_f   = (const float*)d_in[19];
    const float* b_i   = (const float*)d_in[20];
    const float* b_C   = (const float*)d_in[21];
    const float* b_o   = (const float*)d_in[22];
    const float* b_f1  = (const float*)d_in[23];
    const float* b_i1  = (const float*)d_in[24];
    const float* b_C1  = (const float*)d_in[25];
    const float* b_o1  = (const float*)d_in[26];
    const float* b_out = (const float*)d_in[27];
    float* out = (float*)d_out;

    // workspace carve
    uint8_t* ws = (uint8_t*)d_ws;
    const size_t SZ_WCAT0 = (size_t)1536 * NG * 2;    // 12 MB
    const size_t SZ_WCAT1 = (size_t)2048 * NG * 2;    // 16 MB
    const size_t SZ_WOUTP = (size_t)1024 * NOP * 2;   // ~20 MB
    const size_t SZ_E     = (size_t)SEQ * BATCH * EMB * 2;   // 8 MB
    const size_t SZ_H     = (size_t)SEQ * BATCH * HID * 2;   // 16 MB
    const size_t SZ_HB    = (size_t)BATCH * HID * 2;         // 128 KB
    u16*   Wcat0 = (u16*)ws;                         ws += SZ_WCAT0;
    u16*   Wcat1 = (u16*)ws;                         ws += SZ_WCAT1;
    u16*   WoutP = (u16*)ws;                         ws += SZ_WOUTP;
    u16*   E     = (u16*)ws;                         ws += SZ_E;
    u16*   H     = (u16*)ws;                         ws += SZ_H;
    u16*   h0a   = (u16*)ws;                         ws += SZ_HB;
    u16*   h0b   = (u16*)ws;                         ws += SZ_HB;
    u16*   h1a   = (u16*)ws;                         ws += SZ_HB;
    u16*   h1b   = (u16*)ws;                         ws += SZ_HB;
    unsigned* syncw = (unsigned*)ws;                 ws += 1024;

    // allow 147968 B dynamic LDS (idempotent host-side call; capture-safe)
    hipFuncSetAttribute((const void*)persist_k,
                        hipFuncAttributeMaxDynamicSharedMemorySize, LDS_BYTES);

    // --- pack weights + embed (parallel prep work)
    pack_gates<<<256, 256, 0, stream>>>(W_fx, W_ix, W_Cx, W_ox, Wcat0, 64, 0);
    pack_gates<<<512, 256, 0, stream>>>(W_fh, W_ih, W_Ch, W_oh, Wcat0, 128, 64);
    pack_gates<<<512, 256, 0, stream>>>(W_fx1, W_ix1, W_Cx1, W_ox1, Wcat1, 128, 0);
    pack_gates<<<512, 256, 0, stream>>>(W_fh1, W_ih, W_Ch1, W_oh1, Wcat1, 128, 128);
    hipMemsetAsync(WoutP, 0, SZ_WOUTP, stream);
    pack_wout<<<(128 * NCLS + 255) / 256, 256, 0, stream>>>(W_out, WoutP);
    embed_k<<<SEQ * BATCH, 128, 0, stream>>>(X, C, E);

    // --- zero h state + sync counters (ws is re-poisoned before every call)
    hipMemsetAsync(h0a, 0, SZ_HB, stream);
    hipMemsetAsync(h1a, 0, SZ_HB, stream);
    hipMemsetAsync(syncw, 0, 1024, stream);

    // --- the whole recurrence in one launch
    PArgs pa;
    pa.E = E; pa.Wcat0 = Wcat0; pa.Wcat1 = Wcat1;
    pa.H = H; pa.h0a = h0a; pa.h0b = h0b; pa.h1a = h1a; pa.h1b = h1b;
    pa.b_f = b_f; pa.b_i = b_i; pa.b_C = b_C; pa.b_o = b_o;
    pa.b_f1 = b_f1; pa.b_i1 = b_i1; pa.b_C1 = b_C1; pa.b_o1 = b_o1;
    pa.sync = syncw;
    persist_k<<<256, 256, LDS_BYTES, stream>>>(pa);

    // --- output projection (kernel boundary = full coherence for h1a)
    out_gemm<<<314, 256, 0, stream>>>(h1a, WoutP, b_out, out);
}

// Round 5
// 1689.638 us; speedup vs baseline: 5.6579x; 3.7508x over previous
//
#include <hip/hip_runtime.h>
#include <cstdint>
#include <cstddef>

#define BATCH 64
#define SEQ   128
#define EMB   512
#define HID   1024
#define NCLS  10000
#define NG    4096      // 4*HID gate columns
#define NOP   10048     // padded output columns (314 * 32)

typedef __attribute__((ext_vector_type(8))) short short8;
typedef __attribute__((ext_vector_type(4))) short short4v;
typedef __attribute__((ext_vector_type(4))) float floatx4;
typedef unsigned short u16;

// dynamic LDS: 128 KB W slice + red[2][64][33] fp32
#define LDS_W_U16  65536
#define LDS_BYTES  (131072 + 2*64*33*4)   // 147968

__device__ __forceinline__ u16 f2bf(float x) {
    union { float f; unsigned u; } v; v.f = x;
    unsigned r = v.u + 0x7fffu + ((v.u >> 16) & 1u);   // RNE
    return (u16)(r >> 16);
}
__device__ __forceinline__ float sigm(float x) { return 1.f / (1.f + __expf(-x)); }

__device__ __forceinline__ void wait_ge(unsigned* p, unsigned tgt) {
    while (__hip_atomic_load(p, __ATOMIC_RELAXED, __HIP_MEMORY_SCOPE_AGENT) < tgt)
        __builtin_amdgcn_s_sleep(2);
}

// ---------------------------------------------------------------------------
// Pack 4 gate matrices [K][1024] fp32 -> Wcat k-inner-8 bf16 layout:
//   element (k, col n) at dst[((k>>3)*NG + n)*8 + (k&7)],  n = unit*4 + gate.
// ---------------------------------------------------------------------------
__global__ void pack_gates(const float* __restrict__ s0, const float* __restrict__ s1,
                           const float* __restrict__ s2, const float* __restrict__ s3,
                           u16* __restrict__ dst, int kgroups, int kg_off) {
    int t = blockIdx.x * blockDim.x + threadIdx.x;
    if (t >= kgroups * HID) return;
    int u  = t & (HID - 1);
    int kg = t >> 10;
    u16* out = dst + ((size_t)(kg + kg_off) * NG + (size_t)u * 4) * 8;
#pragma unroll
    for (int g = 0; g < 4; ++g) {
        const float* s = (g == 0) ? s0 : (g == 1) ? s1 : (g == 2) ? s2 : s3;
        short8 v;
#pragma unroll
        for (int j = 0; j < 8; ++j)
            v[j] = (short)f2bf(s[(size_t)(kg * 8 + j) * HID + u]);
        *(short8*)(out + g * 8) = v;
    }
}

// W_out [1024][10000] fp32 -> padded k-inner-8 bf16 [(128)][10048][8]
__global__ void pack_wout(const float* __restrict__ src, u16* __restrict__ dst) {
    int t = blockIdx.x * blockDim.x + threadIdx.x;
    if (t >= 128 * NCLS) return;
    int n  = t % NCLS;
    int kg = t / NCLS;
    short8 v;
#pragma unroll
    for (int j = 0; j < 8; ++j)
        v[j] = (short)f2bf(src[(size_t)(kg * 8 + j) * NCLS + n]);
    *(short8*)(dst + ((size_t)kg * NOP + n) * 8) = v;
}

// E[s][b][:] = bf16(C[X[b][s]][:])   (E laid out [SEQ][BATCH][EMB])
__global__ void embed_k(const int* __restrict__ X, const float* __restrict__ C,
                        u16* __restrict__ E) {
    const int sb = blockIdx.x;             // s*64 + m
    const int s = sb >> 6, m = sb & 63;
    const int row = X[m * SEQ + s];
    const floatx4* src = (const floatx4*)(C + (size_t)row * EMB);
    u16* dst = E + (size_t)sb * EMB;
    const int t = threadIdx.x;             // 128 threads, 4 elems each
    floatx4 v = src[t];
    short4v o;
    o[0] = (short)f2bf(v[0]); o[1] = (short)f2bf(v[1]);
    o[2] = (short)f2bf(v[2]); o[3] = (short)f2bf(v[3]);
    *(short4v*)(dst + t * 4) = o;
}

// ---------------------------------------------------------------------------
// One LSTM step, 512 threads = 8 waves: w = km + 2*mw (2-way K x 4-way M).
// Wave (km,mw): rows mw*16..+15, 32 cols, k-half km. B from LDS, A cached.
// Epilogue: 1 thread per (m,u): m=tid>>3, u=tid&7. h written via agent-scope
// relaxed atomic stores (sc1 write-through to L3 -> no dirty L2, no wbl2).
// ---------------------------------------------------------------------------
template<int K1, int CHH, bool WRITE_H>
__device__ __forceinline__ void step_dev(
    u16* __restrict__ WL, float (*red)[64][33],
    const u16* __restrict__ Xt, const u16* __restrict__ hin,
    u16* __restrict__ ho, u16* __restrict__ Hout,
    float& c, float bF, float bI, float bC, float bO, int ub)
{
    const int tid = threadIdx.x;
    const int w = tid >> 6, l = tid & 63;
    const int ml = l & 15, q = l >> 4;
    const int km = w & 1, mw = w >> 1;
    const int row = mw * 16 + ml;

    floatx4 acc0 = {0.f, 0.f, 0.f, 0.f}, acc1 = {0.f, 0.f, 0.f, 0.f};

#pragma unroll
    for (int ci = 0; ci < CHH; ++ci) {
        const int k = (km * CHH + ci) * 32;           // wave-uniform global k
        const u16* Ab; int lda, kl;
        if (k < K1) { Ab = Xt;  lda = K1;  kl = k; }
        else        { Ab = hin; lda = HID; kl = k - K1; }
        const u16* ar = Ab + (size_t)row * lda + kl + q * 8;
        short8 a0 = *(const short8*)ar;
        const u16* br = WL + ((size_t)((k >> 3) + q) * 32 + ml) * 8;
        short8 b0 = *(const short8*)br;
        short8 b1 = *(const short8*)(br + 16 * 8);
        acc0 = __builtin_amdgcn_mfma_f32_16x16x32_bf16(a0, b0, acc0, 0, 0, 0);
        acc1 = __builtin_amdgcn_mfma_f32_16x16x32_bf16(a0, b1, acc1, 0, 0, 0);
    }

#pragma unroll
    for (int r = 0; r < 4; ++r) {
        red[km][mw * 16 + q * 4 + r][ml]      = acc0[r];
        red[km][mw * 16 + q * 4 + r][16 + ml] = acc1[r];
    }
    __syncthreads();

    const int m = tid >> 3, u = tid & 7;
    const int nl = u * 4;
    const int ug = ub * 8 + u;
    float p0 = red[0][m][nl + 0] + red[1][m][nl + 0];
    float p1 = red[0][m][nl + 1] + red[1][m][nl + 1];
    float p2 = red[0][m][nl + 2] + red[1][m][nl + 2];
    float p3 = red[0][m][nl + 3] + red[1][m][nl + 3];
    float f = sigm(p0 + bF);
    float i = sigm(p1 + bI);
    float g = tanhf(p2 + bC);
    float o = sigm(p3 + bO);
    float cc = f * c + i * g;
    c = cc;
    u16 hb = f2bf(o * tanhf(cc));
    __hip_atomic_store(&ho[(size_t)m * HID + ug], hb,
                       __ATOMIC_RELAXED, __HIP_MEMORY_SCOPE_AGENT);
    if (WRITE_H)
        __hip_atomic_store(&Hout[(size_t)m * HID + ug], hb,
                           __ATOMIC_RELAXED, __HIP_MEMORY_SCOPE_AGENT);
}

// ---------------------------------------------------------------------------
// Persistent kernel. 256 blocks x 512 thr, 147968 B LDS -> 1 block/CU,
// grid == #CUs: co-resident under a normal launch.
// Coherence protocol (the round-3 lesson):
//   - producers: sc1 write-through atomic stores; NO release fences (no wbl2)
//   - consumers: relaxed poll; ONE acquire fence (buffer_inv) per tick;
//     all data loads normal/cached (A-broadcast stays L2-resident)
// ---------------------------------------------------------------------------
struct PArgs {
    const u16 *E, *Wcat0, *Wcat1;
    u16 *H, *h0a, *h0b, *h1a, *h1b;
    const float *b_f, *b_i, *b_C, *b_o, *b_f1, *b_i1, *b_C1, *b_o1;
    unsigned* sync;   // [0]=bar0, [64]=bar1, [128]=hcnt (separate cachelines)
};

__global__ void __launch_bounds__(512, 1) persist_k(PArgs a) {
    extern __shared__ u16 lds[];
    u16* WL = lds;
    float (*red)[64][33] = (float (*)[64][33])(lds + LDS_W_U16);

    const int b   = blockIdx.x;
    const int ub  = b & 127;
    const int tid = threadIdx.x;
    const bool L0 = (b < 128);

    // stage this block's W slice into LDS (k-inner-8, 32 local cols)
    {
        const u16* Wsrc = L0 ? a.Wcat0 : a.Wcat1;
        const int  kgs  = L0 ? 192 : 256;
        for (int i2 = tid; i2 < kgs * 32; i2 += 512) {
            const int kg = i2 >> 5, cc2 = i2 & 31;
            *(short8*)(WL + ((size_t)(kg * 32 + cc2)) * 8) =
                *(const short8*)(Wsrc + ((size_t)kg * NG + ub * 32 + cc2) * 8);
        }
    }

    // per-thread epilogue state (mapping fixed across ticks)
    const int ug = ub * 8 + (tid & 7);
    const float bF = L0 ? a.b_f[ug] : a.b_f1[ug];
    const float bI = L0 ? a.b_i[ug] : a.b_i1[ug];
    const float bC = L0 ? a.b_C[ug] : a.b_C1[ug];
    const float bO = L0 ? a.b_o[ug] : a.b_o1[ug];
    float c = 0.f;

    unsigned* bar0 = a.sync;
    unsigned* bar1 = a.sync + 64;
    unsigned* hcnt = a.sync + 128;
    __syncthreads();

    if (L0) {
        for (int t = 0; t < 128; ++t) {
            if (tid == 0 && t > 0) {
                wait_ge(bar0, 128u * (unsigned)t);
                __builtin_amdgcn_fence(__ATOMIC_ACQUIRE, "agent");  // 1 inv, 0 wbl2
            }
            __syncthreads();
            const u16* hin = (t & 1) ? a.h0b : a.h0a;
            u16*       ho  = (t & 1) ? a.h0a : a.h0b;
            step_dev<512, 24, true>(WL, red, a.E + (size_t)t * BATCH * EMB, hin, ho,
                                    a.H + (size_t)t * BATCH * HID, c, bF, bI, bC, bO, ub);
            asm volatile("s_waitcnt vmcnt(0)" ::: "memory");  // stores at L3
            __syncthreads();
            if (tid == 0) {
                __hip_atomic_fetch_add(hcnt, 1u, __ATOMIC_RELAXED, __HIP_MEMORY_SCOPE_AGENT);
                __hip_atomic_fetch_add(bar0, 1u, __ATOMIC_RELAXED, __HIP_MEMORY_SCOPE_AGENT);
            }
        }
    } else {
        for (int s = 0; s < 128; ++s) {
            if (tid == 0) {
                wait_ge(hcnt, 128u * (unsigned)(s + 1));      // H[s] ready
                if (s > 0) wait_ge(bar1, 128u * (unsigned)s); // h1 WAR
                __builtin_amdgcn_fence(__ATOMIC_ACQUIRE, "agent");
            }
            __syncthreads();
            const u16* hin = (s & 1) ? a.h1b : a.h1a;
            u16*       ho  = (s & 1) ? a.h1a : a.h1b;
            step_dev<1024, 32, false>(WL, red, a.H + (size_t)s * BATCH * HID, hin, ho,
                                      nullptr, c, bF, bI, bC, bO, ub);
            asm volatile("s_waitcnt vmcnt(0)" ::: "memory");
            __syncthreads();
            if (tid == 0)
                __hip_atomic_fetch_add(bar1, 1u, __ATOMIC_RELAXED, __HIP_MEMORY_SCOPE_AGENT);
        }
    }
    // final h1 in h1a; out_gemm is a separate launch (kernel-boundary coherence)
}

// out[64][10000] = h1 @ W_out + b_out   (314 blocks x 32 cols) — round-1 verified
__global__ void __launch_bounds__(256) out_gemm(
    const u16* __restrict__ h1, const u16* __restrict__ W,
    const float* __restrict__ bout, float* __restrict__ out)
{
    __shared__ float red[4][64][33];
    const int tid = threadIdx.x;
    const int w = tid >> 6, l = tid & 63;
    const int ml = l & 15, q = l >> 4;
    const int n0 = blockIdx.x * 32;

    floatx4 acc[4][2];
#pragma unroll
    for (int mi = 0; mi < 4; ++mi)
#pragma unroll
        for (int ni = 0; ni < 2; ++ni)
            acc[mi][ni] = (floatx4){0.f, 0.f, 0.f, 0.f};

#pragma unroll
    for (int ci = 0; ci < 8; ++ci) {
        const int k = (ci * 4 + w) << 5;
        const u16* ar = h1 + (size_t)ml * HID + k + q * 8;
        short8 a0 = *(const short8*)(ar);
        short8 a1 = *(const short8*)(ar + 16 * HID);
        short8 a2 = *(const short8*)(ar + 32 * HID);
        short8 a3 = *(const short8*)(ar + 48 * HID);
        const u16* br = W + ((size_t)((k >> 3) + q) * NOP + n0 + ml) * 8;
        short8 b0 = *(const short8*)(br);
        short8 b1 = *(const short8*)(br + 16 * 8);
        acc[0][0] = __builtin_amdgcn_mfma_f32_16x16x32_bf16(a0, b0, acc[0][0], 0, 0, 0);
        acc[1][0] = __builtin_amdgcn_mfma_f32_16x16x32_bf16(a1, b0, acc[1][0], 0, 0, 0);
        acc[2][0] = __builtin_amdgcn_mfma_f32_16x16x32_bf16(a2, b0, acc[2][0], 0, 0, 0);
        acc[3][0] = __builtin_amdgcn_mfma_f32_16x16x32_bf16(a3, b0, acc[3][0], 0, 0, 0);
        acc[0][1] = __builtin_amdgcn_mfma_f32_16x16x32_bf16(a0, b1, acc[0][1], 0, 0, 0);
        acc[1][1] = __builtin_amdgcn_mfma_f32_16x16x32_bf16(a1, b1, acc[1][1], 0, 0, 0);
        acc[2][1] = __builtin_amdgcn_mfma_f32_16x16x32_bf16(a2, b1, acc[2][1], 0, 0, 0);
        acc[3][1] = __builtin_amdgcn_mfma_f32_16x16x32_bf16(a3, b1, acc[3][1], 0, 0, 0);
    }

#pragma unroll
    for (int mi = 0; mi < 4; ++mi)
#pragma unroll
        for (int ni = 0; ni < 2; ++ni)
#pragma unroll
            for (int r = 0; r < 4; ++r)
                red[w][mi * 16 + q * 4 + r][ni * 16 + ml] = acc[mi][ni][r];
    __syncthreads();

    const int m = tid >> 2;
#pragma unroll
    for (int jj = 0; jj < 8; ++jj) {
        const int nl = (tid & 3) * 8 + jj;
        const int n = n0 + nl;
        if (n < NCLS) {
            float v = red[0][m][nl] + red[1][m][nl] + red[2][m][nl] + red[3][m][nl] + bout[n];
            out[(size_t)m * NCLS + n] = v;
        }
    }
}

// ---------------------------------------------------------------------------
extern "C" void kernel_launch(void* const* d_in, const int* in_sizes, int n_in,
                              void* d_out, int out_size, void* d_ws, size_t ws_size,
                              hipStream_t stream) {
    (void)in_sizes; (void)n_in; (void)out_size; (void)ws_size;
    const int*   X     = (const int*)  d_in[0];
    const float* C     = (const float*)d_in[1];
    const float* W_fx  = (const float*)d_in[2];
    const float* W_fh  = (const float*)d_in[3];
    const float* W_ix  = (const float*)d_in[4];
    const float* W_ih  = (const float*)d_in[5];
    const float* W_Cx  = (const float*)d_in[6];
    const float* W_Ch  = (const float*)d_in[7];
    const float* W_ox  = (const float*)d_in[8];
    const float* W_oh  = (const float*)d_in[9];
    const float* W_fx1 = (const float*)d_in[10];
    const float* W_fh1 = (const float*)d_in[11];
    const float* W_ix1 = (const float*)d_in[12];
    // d_in[13] = W_ih1 — unused: reference reuses W_ih in layer-1 i-gate (bug kept)
    const float* W_Cx1 = (const float*)d_in[14];
    const float* W_Ch1 = (const float*)d_in[15];
    const float* W_ox1 = (const float*)d_in[16];
    const float* W_oh1 = (const float*)d_in[17];
    const float* W_out = (const float*)d_in[18];
    const float* b_f   = (const float*)d_in[19];
    const float* b_i   = (const float*)d_in[20];
    const float* b_C   = (const float*)d_in[21];
    const float* b_o   = (const float*)d_in[22];
    const float* b_f1  = (const float*)d_in[23];
    const float* b_i1  = (const float*)d_in[24];
    const float* b_C1  = (const float*)d_in[25];
    const float* b_o1  = (const float*)d_in[26];
    const float* b_out = (const float*)d_in[27];
    float* out = (float*)d_out;

    // workspace carve
    uint8_t* ws = (uint8_t*)d_ws;
    const size_t SZ_WCAT0 = (size_t)1536 * NG * 2;    // 12 MB
    const size_t SZ_WCAT1 = (size_t)2048 * NG * 2;    // 16 MB
    const size_t SZ_WOUTP = (size_t)1024 * NOP * 2;   // ~20 MB
    const size_t SZ_E     = (size_t)SEQ * BATCH * EMB * 2;   // 8 MB
    const size_t SZ_H     = (size_t)SEQ * BATCH * HID * 2;   // 16 MB
    const size_t SZ_HB    = (size_t)BATCH * HID * 2;         // 128 KB
    u16*   Wcat0 = (u16*)ws;                         ws += SZ_WCAT0;
    u16*   Wcat1 = (u16*)ws;                         ws += SZ_WCAT1;
    u16*   WoutP = (u16*)ws;                         ws += SZ_WOUTP;
    u16*   E     = (u16*)ws;                         ws += SZ_E;
    u16*   H     = (u16*)ws;                         ws += SZ_H;
    u16*   h0a   = (u16*)ws;                         ws += SZ_HB;
    u16*   h0b   = (u16*)ws;                         ws += SZ_HB;
    u16*   h1a   = (u16*)ws;                         ws += SZ_HB;
    u16*   h1b   = (u16*)ws;                         ws += SZ_HB;
    unsigned* syncw = (unsigned*)ws;                 ws += 1024;

    // allow 147968 B dynamic LDS (host-side, capture-safe; validated round 3)
    hipFuncSetAttribute((const void*)persist_k,
                        hipFuncAttributeMaxDynamicSharedMemorySize, LDS_BYTES);

    // --- pack weights + embed (parallel prep work)
    pack_gates<<<256, 256, 0, stream>>>(W_fx, W_ix, W_Cx, W_ox, Wcat0, 64, 0);
    pack_gates<<<512, 256, 0, stream>>>(W_fh, W_ih, W_Ch, W_oh, Wcat0, 128, 64);
    pack_gates<<<512, 256, 0, stream>>>(W_fx1, W_ix1, W_Cx1, W_ox1, Wcat1, 128, 0);
    pack_gates<<<512, 256, 0, stream>>>(W_fh1, W_ih, W_Ch1, W_oh1, Wcat1, 128, 128);
    hipMemsetAsync(WoutP, 0, SZ_WOUTP, stream);
    pack_wout<<<(128 * NCLS + 255) / 256, 256, 0, stream>>>(W_out, WoutP);
    embed_k<<<SEQ * BATCH, 128, 0, stream>>>(X, C, E);

    // --- zero h state + sync counters (ws is re-poisoned before every call)
    hipMemsetAsync(h0a, 0, SZ_HB, stream);
    hipMemsetAsync(h1a, 0, SZ_HB, stream);
    hipMemsetAsync(syncw, 0, 1024, stream);

    // --- the whole recurrence in one launch
    PArgs pa;
    pa.E = E; pa.Wcat0 = Wcat0; pa.Wcat1 = Wcat1;
    pa.H = H; pa.h0a = h0a; pa.h0b = h0b; pa.h1a = h1a; pa.h1b = h1b;
    pa.b_f = b_f; pa.b_i = b_i; pa.b_C = b_C; pa.b_o = b_o;
    pa.b_f1 = b_f1; pa.b_i1 = b_i1; pa.b_C1 = b_C1; pa.b_o1 = b_o1;
    pa.sync = syncw;
    persist_k<<<256, 512, LDS_BYTES, stream>>>(pa);

    // --- output projection (kernel boundary = full coherence for h1a)
    out_gemm<<<314, 256, 0, stream>>>(h1a, WoutP, b_out, out);
}

// Round 6
// 1504.512 us; speedup vs baseline: 6.3541x; 1.1230x over previous
//
#include <hip/hip_runtime.h>
#include <cstdint>
#include <cstddef>

#define BATCH 64
#define SEQ   128
#define EMB   512
#define HID   1024
#define NCLS  10000
#define NG    4096      // 4*HID gate columns
#define NOP   10048     // padded output columns (314 * 32)
#define BH    (BATCH * HID)   // one h slot (elements)

typedef __attribute__((ext_vector_type(8))) short short8;
typedef __attribute__((ext_vector_type(4))) short short4v;
typedef __attribute__((ext_vector_type(4))) float floatx4;
typedef unsigned short u16;

// dynamic LDS: 128 KB W slice + red[2][64][33] fp32
#define LDS_W_U16  65536
#define LDS_BYTES  (131072 + 2*64*33*4)   // 147968

__device__ __forceinline__ u16 f2bf(float x) {
    union { float f; unsigned u; } v; v.f = x;
    unsigned r = v.u + 0x7fffu + ((v.u >> 16) & 1u);   // RNE
    return (u16)(r >> 16);
}
__device__ __forceinline__ float sigm(float x) { return 1.f / (1.f + __expf(-x)); }

__device__ __forceinline__ void wait_ge(unsigned* p, unsigned tgt) {
    while (__hip_atomic_load(p, __ATOMIC_RELAXED, __HIP_MEMORY_SCOPE_AGENT) < tgt)
        __builtin_amdgcn_s_sleep(4);
}

// ---------------------------------------------------------------------------
// Pack 4 gate matrices [K][1024] fp32 -> Wcat k-inner-8 bf16 layout:
//   element (k, col n) at dst[((k>>3)*NG + n)*8 + (k&7)],  n = unit*4 + gate.
// ---------------------------------------------------------------------------
__global__ void pack_gates(const float* __restrict__ s0, const float* __restrict__ s1,
                           const float* __restrict__ s2, const float* __restrict__ s3,
                           u16* __restrict__ dst, int kgroups, int kg_off) {
    int t = blockIdx.x * blockDim.x + threadIdx.x;
    if (t >= kgroups * HID) return;
    int u  = t & (HID - 1);
    int kg = t >> 10;
    u16* out = dst + ((size_t)(kg + kg_off) * NG + (size_t)u * 4) * 8;
#pragma unroll
    for (int g = 0; g < 4; ++g) {
        const float* s = (g == 0) ? s0 : (g == 1) ? s1 : (g == 2) ? s2 : s3;
        short8 v;
#pragma unroll
        for (int j = 0; j < 8; ++j)
            v[j] = (short)f2bf(s[(size_t)(kg * 8 + j) * HID + u]);
        *(short8*)(out + g * 8) = v;
    }
}

// W_out [1024][10000] fp32 -> padded k-inner-8 bf16 [(128)][10048][8]
__global__ void pack_wout(const float* __restrict__ src, u16* __restrict__ dst) {
    int t = blockIdx.x * blockDim.x + threadIdx.x;
    if (t >= 128 * NCLS) return;
    int n  = t % NCLS;
    int kg = t / NCLS;
    short8 v;
#pragma unroll
    for (int j = 0; j < 8; ++j)
        v[j] = (short)f2bf(src[(size_t)(kg * 8 + j) * NCLS + n]);
    *(short8*)(dst + ((size_t)kg * NOP + n) * 8) = v;
}

// E[s][b][:] = bf16(C[X[b][s]][:])   (E laid out [SEQ][BATCH][EMB])
__global__ void embed_k(const int* __restrict__ X, const float* __restrict__ C,
                        u16* __restrict__ E) {
    const int sb = blockIdx.x;             // s*64 + m
    const int s = sb >> 6, m = sb & 63;
    const int row = X[m * SEQ + s];
    const floatx4* src = (const floatx4*)(C + (size_t)row * EMB);
    u16* dst = E + (size_t)sb * EMB;
    const int t = threadIdx.x;             // 128 threads, 4 elems each
    floatx4 v = src[t];
    short4v o;
    o[0] = (short)f2bf(v[0]); o[1] = (short)f2bf(v[1]);
    o[2] = (short)f2bf(v[2]); o[3] = (short)f2bf(v[3]);
    *(short4v*)(dst + t * 4) = o;
}

// ---------------------------------------------------------------------------
// One LSTM step, 512 threads = 8 waves: w = km + 2*mw (2-way K x 4-way M).
// Wave (km,mw): rows mw*16..+15, 32 cols, k-half km. B from LDS, A cached.
// Epilogue: 1 thread per (m,u). h written via agent-scope relaxed atomic
// stores (sc1 write-through to L3 -> no dirty L2, L3 always fresh).
// ---------------------------------------------------------------------------
template<int K1, int CHH, bool WRITE_H>
__device__ __forceinline__ void step_dev(
    u16* __restrict__ WL, float (*red)[64][33],
    const u16* __restrict__ Xt, const u16* __restrict__ hin,
    u16* __restrict__ ho, u16* __restrict__ Hout,
    float& c, float bF, float bI, float bC, float bO, int ub)
{
    const int tid = threadIdx.x;
    const int w = tid >> 6, l = tid & 63;
    const int ml = l & 15, q = l >> 4;
    const int km = w & 1, mw = w >> 1;
    const int row = mw * 16 + ml;

    floatx4 acc0 = {0.f, 0.f, 0.f, 0.f}, acc1 = {0.f, 0.f, 0.f, 0.f};

#pragma unroll
    for (int ci = 0; ci < CHH; ++ci) {
        const int k = (km * CHH + ci) * 32;           // wave-uniform global k
        const u16* Ab; int lda, kl;
        if (k < K1) { Ab = Xt;  lda = K1;  kl = k; }
        else        { Ab = hin; lda = HID; kl = k - K1; }
        const u16* ar = Ab + (size_t)row * lda + kl + q * 8;
        short8 a0 = *(const short8*)ar;
        const u16* br = WL + ((size_t)((k >> 3) + q) * 32 + ml) * 8;
        short8 b0 = *(const short8*)br;
        short8 b1 = *(const short8*)(br + 16 * 8);
        acc0 = __builtin_amdgcn_mfma_f32_16x16x32_bf16(a0, b0, acc0, 0, 0, 0);
        acc1 = __builtin_amdgcn_mfma_f32_16x16x32_bf16(a0, b1, acc1, 0, 0, 0);
    }

#pragma unroll
    for (int r = 0; r < 4; ++r) {
        red[km][mw * 16 + q * 4 + r][ml]      = acc0[r];
        red[km][mw * 16 + q * 4 + r][16 + ml] = acc1[r];
    }
    __syncthreads();

    const int m = tid >> 3, u = tid & 7;
    const int nl = u * 4;
    const int ug = ub * 8 + u;
    float p0 = red[0][m][nl + 0] + red[1][m][nl + 0];
    float p1 = red[0][m][nl + 1] + red[1][m][nl + 1];
    float p2 = red[0][m][nl + 2] + red[1][m][nl + 2];
    float p3 = red[0][m][nl + 3] + red[1][m][nl + 3];
    float f = sigm(p0 + bF);
    float i = sigm(p1 + bI);
    float g = tanhf(p2 + bC);
    float o = sigm(p3 + bO);
    float cc = f * c + i * g;
    c = cc;
    u16 hb = f2bf(o * tanhf(cc));
    __hip_atomic_store(&ho[(size_t)m * HID + ug], hb,
                       __ATOMIC_RELAXED, __HIP_MEMORY_SCOPE_AGENT);
    if (WRITE_H)
        __hip_atomic_store(&Hout[(size_t)m * HID + ug], hb,
                           __ATOMIC_RELAXED, __HIP_MEMORY_SCOPE_AGENT);
}

// ---------------------------------------------------------------------------
// Persistent kernel. 256 blocks x 512 thr, 147968 B LDS -> 1 block/CU.
// Round-6 coherence design: NO fences in the tick loop.
//   - h0/h1 are 129-slot per-tick chains; H is per-tick. A consumer's L2
//     can only acquire these lines via a fresh L3 fill (addresses untouched
//     earlier in this launch; dispatch-time acquire invalidated L2).
//   - producers: sc1 write-through stores -> L3 always fresh, L2 never dirty.
//   - barrier arrivals spread over 16 cachelines (8 adds/line), waiters
//     tid 0..15 poll one line each, joined by __syncthreads.
// ---------------------------------------------------------------------------
struct PArgs {
    const u16 *E, *Wcat0, *Wcat1;
    u16 *H, *h0c, *h1c;     // h chains: 129 slots of [64][1024]
    const float *b_f, *b_i, *b_C, *b_o, *b_f1, *b_i1, *b_C1, *b_o1;
    unsigned* sync;          // bar0[16 lines], bar1[16], hcnt[16]; line = 32 uints
};

__global__ void __launch_bounds__(512, 1) persist_k(PArgs a) {
    extern __shared__ u16 lds[];
    u16* WL = lds;
    float (*red)[64][33] = (float (*)[64][33])(lds + LDS_W_U16);

    const int b   = blockIdx.x;
    const int ub  = b & 127;
    const int tid = threadIdx.x;
    const bool L0 = (b < 128);

    // stage this block's W slice into LDS (k-inner-8, 32 local cols)
    {
        const u16* Wsrc = L0 ? a.Wcat0 : a.Wcat1;
        const int  kgs  = L0 ? 192 : 256;
        for (int i2 = tid; i2 < kgs * 32; i2 += 512) {
            const int kg = i2 >> 5, cc2 = i2 & 31;
            *(short8*)(WL + ((size_t)(kg * 32 + cc2)) * 8) =
                *(const short8*)(Wsrc + ((size_t)kg * NG + ub * 32 + cc2) * 8);
        }
    }

    // per-thread epilogue state (mapping fixed across ticks)
    const int ug = ub * 8 + (tid & 7);
    const float bF = L0 ? a.b_f[ug] : a.b_f1[ug];
    const float bI = L0 ? a.b_i[ug] : a.b_i1[ug];
    const float bC = L0 ? a.b_C[ug] : a.b_C1[ug];
    const float bO = L0 ? a.b_o[ug] : a.b_o1[ug];
    float c = 0.f;

    unsigned* bar0 = a.sync;               // 16 lines x 32 uints
    unsigned* bar1 = a.sync + 512;
    unsigned* hcnt = a.sync + 1024;
    const int lane16 = (ub & 15) * 32;     // this block's arrive line
    __syncthreads();

    if (L0) {
        for (int t = 0; t < 128; ++t) {
            if (t > 0) {
                if (tid < 16) wait_ge(bar0 + tid * 32, 8u * (unsigned)t);
                asm volatile("" ::: "memory");
            }
            __syncthreads();
            const u16* hin = a.h0c + (size_t)t * BH;
            u16*       ho  = a.h0c + (size_t)(t + 1) * BH;
            step_dev<512, 24, true>(WL, red, a.E + (size_t)t * BATCH * EMB, hin, ho,
                                    a.H + (size_t)t * BH, c, bF, bI, bC, bO, ub);
            asm volatile("s_waitcnt vmcnt(0)" ::: "memory");  // stores at L3
            __syncthreads();
            if (tid == 0) {
                __hip_atomic_fetch_add(hcnt + lane16, 1u, __ATOMIC_RELAXED, __HIP_MEMORY_SCOPE_AGENT);
                __hip_atomic_fetch_add(bar0 + lane16, 1u, __ATOMIC_RELAXED, __HIP_MEMORY_SCOPE_AGENT);
            }
        }
    } else {
        for (int s = 0; s < 128; ++s) {
            if (tid < 16)      wait_ge(hcnt + tid * 32, 8u * (unsigned)(s + 1));
            else if (tid < 32 && s > 0)
                               wait_ge(bar1 + (tid - 16) * 32, 8u * (unsigned)s);
            asm volatile("" ::: "memory");
            __syncthreads();
            const u16* hin = a.h1c + (size_t)s * BH;
            u16*       ho  = a.h1c + (size_t)(s + 1) * BH;
            step_dev<1024, 32, false>(WL, red, a.H + (size_t)s * BH, hin, ho,
                                      nullptr, c, bF, bI, bC, bO, ub);
            asm volatile("s_waitcnt vmcnt(0)" ::: "memory");
            __syncthreads();
            if (tid == 0)
                __hip_atomic_fetch_add(bar1 + lane16, 1u, __ATOMIC_RELAXED, __HIP_MEMORY_SCOPE_AGENT);
        }
    }
    // final h1 = h1c + 128*BH; out_gemm is a separate launch (boundary coherence)
}

// out[64][10000] = h1 @ W_out + b_out   (314 blocks x 32 cols) — round-1 verified
__global__ void __launch_bounds__(256) out_gemm(
    const u16* __restrict__ h1, const u16* __restrict__ W,
    const float* __restrict__ bout, float* __restrict__ out)
{
    __shared__ float red[4][64][33];
    const int tid = threadIdx.x;
    const int w = tid >> 6, l = tid & 63;
    const int ml = l & 15, q = l >> 4;
    const int n0 = blockIdx.x * 32;

    floatx4 acc[4][2];
#pragma unroll
    for (int mi = 0; mi < 4; ++mi)
#pragma unroll
        for (int ni = 0; ni < 2; ++ni)
            acc[mi][ni] = (floatx4){0.f, 0.f, 0.f, 0.f};

#pragma unroll
    for (int ci = 0; ci < 8; ++ci) {
        const int k = (ci * 4 + w) << 5;
        const u16* ar = h1 + (size_t)ml * HID + k + q * 8;
        short8 a0 = *(const short8*)(ar);
        short8 a1 = *(const short8*)(ar + 16 * HID);
        short8 a2 = *(const short8*)(ar + 32 * HID);
        short8 a3 = *(const short8*)(ar + 48 * HID);
        const u16* br = W + ((size_t)((k >> 3) + q) * NOP + n0 + ml) * 8;
        short8 b0 = *(const short8*)(br);
        short8 b1 = *(const short8*)(br + 16 * 8);
        acc[0][0] = __builtin_amdgcn_mfma_f32_16x16x32_bf16(a0, b0, acc[0][0], 0, 0, 0);
        acc[1][0] = __builtin_amdgcn_mfma_f32_16x16x32_bf16(a1, b0, acc[1][0], 0, 0, 0);
        acc[2][0] = __builtin_amdgcn_mfma_f32_16x16x32_bf16(a2, b0, acc[2][0], 0, 0, 0);
        acc[3][0] = __builtin_amdgcn_mfma_f32_16x16x32_bf16(a3, b0, acc[3][0], 0, 0, 0);
        acc[0][1] = __builtin_amdgcn_mfma_f32_16x16x32_bf16(a0, b1, acc[0][1], 0, 0, 0);
        acc[1][1] = __builtin_amdgcn_mfma_f32_16x16x32_bf16(a1, b1, acc[1][1], 0, 0, 0);
        acc[2][1] = __builtin_amdgcn_mfma_f32_16x16x32_bf16(a2, b1, acc[2][1], 0, 0, 0);
        acc[3][1] = __builtin_amdgcn_mfma_f32_16x16x32_bf16(a3, b1, acc[3][1], 0, 0, 0);
    }

#pragma unroll
    for (int mi = 0; mi < 4; ++mi)
#pragma unroll
        for (int ni = 0; ni < 2; ++ni)
#pragma unroll
            for (int r = 0; r < 4; ++r)
                red[w][mi * 16 + q * 4 + r][ni * 16 + ml] = acc[mi][ni][r];
    __syncthreads();

    const int m = tid >> 2;
#pragma unroll
    for (int jj = 0; jj < 8; ++jj) {
        const int nl = (tid & 3) * 8 + jj;
        const int n = n0 + nl;
        if (n < NCLS) {
            float v = red[0][m][nl] + red[1][m][nl] + red[2][m][nl] + red[3][m][nl] + bout[n];
            out[(size_t)m * NCLS + n] = v;
        }
    }
}

// ---------------------------------------------------------------------------
extern "C" void kernel_launch(void* const* d_in, const int* in_sizes, int n_in,
                              void* d_out, int out_size, void* d_ws, size_t ws_size,
                              hipStream_t stream) {
    (void)in_sizes; (void)n_in; (void)out_size; (void)ws_size;
    const int*   X     = (const int*)  d_in[0];
    const float* C     = (const float*)d_in[1];
    const float* W_fx  = (const float*)d_in[2];
    const float* W_fh  = (const float*)d_in[3];
    const float* W_ix  = (const float*)d_in[4];
    const float* W_ih  = (const float*)d_in[5];
    const float* W_Cx  = (const float*)d_in[6];
    const float* W_Ch  = (const float*)d_in[7];
    const float* W_ox  = (const float*)d_in[8];
    const float* W_oh  = (const float*)d_in[9];
    const float* W_fx1 = (const float*)d_in[10];
    const float* W_fh1 = (const float*)d_in[11];
    const float* W_ix1 = (const float*)d_in[12];
    // d_in[13] = W_ih1 — unused: reference reuses W_ih in layer-1 i-gate (bug kept)
    const float* W_Cx1 = (const float*)d_in[14];
    const float* W_Ch1 = (const float*)d_in[15];
    const float* W_ox1 = (const float*)d_in[16];
    const float* W_oh1 = (const float*)d_in[17];
    const float* W_out = (const float*)d_in[18];
    const float* b_f   = (const float*)d_in[19];
    const float* b_i   = (const float*)d_in[20];
    const float* b_C   = (const float*)d_in[21];
    const float* b_o   = (const float*)d_in[22];
    const float* b_f1  = (const float*)d_in[23];
    const float* b_i1  = (const float*)d_in[24];
    const float* b_C1  = (const float*)d_in[25];
    const float* b_o1  = (const float*)d_in[26];
    const float* b_out = (const float*)d_in[27];
    float* out = (float*)d_out;

    // workspace carve (~105 MB)
    uint8_t* ws = (uint8_t*)d_ws;
    const size_t SZ_WCAT0 = (size_t)1536 * NG * 2;      // 12 MB
    const size_t SZ_WCAT1 = (size_t)2048 * NG * 2;      // 16 MB
    const size_t SZ_WOUTP = (size_t)1024 * NOP * 2;     // ~20 MB
    const size_t SZ_E     = (size_t)SEQ * BATCH * EMB * 2;    // 8 MB
    const size_t SZ_H     = (size_t)SEQ * BH * 2;             // 16 MB
    const size_t SZ_HC    = (size_t)(SEQ + 1) * BH * 2;       // 16.6 MB per chain
    u16*   Wcat0 = (u16*)ws;                         ws += SZ_WCAT0;
    u16*   Wcat1 = (u16*)ws;                         ws += SZ_WCAT1;
    u16*   WoutP = (u16*)ws;                         ws += SZ_WOUTP;
    u16*   E     = (u16*)ws;                         ws += SZ_E;
    u16*   H     = (u16*)ws;                         ws += SZ_H;
    u16*   h0c   = (u16*)ws;                         ws += SZ_HC;
    u16*   h1c   = (u16*)ws;                         ws += SZ_HC;
    unsigned* syncw = (unsigned*)ws;                 ws += 8192;

    // allow 147968 B dynamic LDS (host-side, capture-safe; validated round 3/5)
    hipFuncSetAttribute((const void*)persist_k,
                        hipFuncAttributeMaxDynamicSharedMemorySize, LDS_BYTES);

    // --- pack weights + embed (parallel prep work)
    pack_gates<<<256, 256, 0, stream>>>(W_fx, W_ix, W_Cx, W_ox, Wcat0, 64, 0);
    pack_gates<<<512, 256, 0, stream>>>(W_fh, W_ih, W_Ch, W_oh, Wcat0, 128, 64);
    pack_gates<<<512, 256, 0, stream>>>(W_fx1, W_ix1, W_Cx1, W_ox1, Wcat1, 128, 0);
    pack_gates<<<512, 256, 0, stream>>>(W_fh1, W_ih, W_Ch1, W_oh1, Wcat1, 128, 128);
    hipMemsetAsync(WoutP, 0, SZ_WOUTP, stream);
    pack_wout<<<(128 * NCLS + 255) / 256, 256, 0, stream>>>(W_out, WoutP);
    embed_k<<<SEQ * BATCH, 128, 0, stream>>>(X, C, E);

    // --- zero slot 0 of both h chains + sync counters
    hipMemsetAsync(h0c, 0, (size_t)BH * 2, stream);
    hipMemsetAsync(h1c, 0, (size_t)BH * 2, stream);
    hipMemsetAsync(syncw, 0, 8192, stream);

    // --- the whole recurrence in one launch
    PArgs pa;
    pa.E = E; pa.Wcat0 = Wcat0; pa.Wcat1 = Wcat1;
    pa.H = H; pa.h0c = h0c; pa.h1c = h1c;
    pa.b_f = b_f; pa.b_i = b_i; pa.b_C = b_C; pa.b_o = b_o;
    pa.b_f1 = b_f1; pa.b_i1 = b_i1; pa.b_C1 = b_C1; pa.b_o1 = b_o1;
    pa.sync = syncw;
    persist_k<<<256, 512, LDS_BYTES, stream>>>(pa);

    // --- output projection (kernel boundary = full coherence for h1c final slot)
    out_gemm<<<314, 256, 0, stream>>>(h1c + (size_t)SEQ * BH, WoutP, b_out, out);
}